// Round 1
// baseline (773.827 us; speedup 1.0000x reference)
//
#include <hip/hip_runtime.h>
#include <math.h>

// ---------------------------------------------------------------------------
// OptimizedProtoHyperFormer — fp32 correctness-first implementation.
// B=32, IB=103, H=W=256, P=16, RB=8, DIM=192, DEPTH=3, KS=KP=24, TOPK=2,
// NC=9, FFH=384. Tokens: hp*wp = 16*16 = 256 per batch, NT = 8192.
// ---------------------------------------------------------------------------

__device__ __forceinline__ float wsum64(float v) {
#pragma unroll
  for (int o = 32; o > 0; o >>= 1) v += __shfl_xor(v, o, 64);
  return v;
}
__device__ __forceinline__ float wmax64(float v) {
#pragma unroll
  for (int o = 32; o > 0; o >>= 1) v = fmaxf(v, __shfl_xor(v, o, 64));
  return v;
}
__device__ __forceinline__ float sum16(float v) {
#pragma unroll
  for (int o = 8; o > 0; o >>= 1) v += __shfl_xor(v, o, 64);
  return v;
}
__device__ __forceinline__ float gelu_f(float x) {
  return 0.5f * x * (1.0f + erff(x * 0.7071067811865476f));
}

// ---------------------------------------------------------------------------
// K1: fused band-reduction (103->8) + depthwise 16x16 patch conv.
// Grid: 32*16 = 512 blocks (one per batch x patch-row), 512 threads.
// Per channel: contiguous 4096-float chunk (rows i*16..i*16+15, all cols).
// Thread t covers float4 cols (t&63), rows {t>>6, (t>>6)+8}.
// ---------------------------------------------------------------------------
__global__ __launch_bounds__(512) void k1_band_dw(
    const float* __restrict__ x, const float* __restrict__ band_w,
    const float* __restrict__ band_b, const float* __restrict__ dw_w,
    float* __restrict__ dw_out) {
  const int blk = blockIdx.x;
  const int b = blk >> 4, ip = blk & 15;
  const int t = threadIdx.x;
  const int col4 = t & 63;
  const int j = col4 >> 2;             // patch col 0..15
  const int qb = (col4 & 3) << 2;      // q base within patch
  const int p0 = t >> 6;               // row 0..7 (second row = p0+8)

  float acc[8][8];
#pragma unroll
  for (int e = 0; e < 8; ++e)
#pragma unroll
    for (int c = 0; c < 8; ++c) acc[e][c] = 0.f;

  const float4* xp = (const float4*)x + (size_t)b * (103 * 16384) + (size_t)ip * 1024;
  for (int ch = 0; ch < 103; ++ch) {
    const float4 v0 = xp[t];
    const float4 v1 = xp[t + 512];
    xp += 16384;  // one channel = 65536 floats = 16384 float4
#pragma unroll
    for (int c = 0; c < 8; ++c) {
      const float bw = band_w[c * 103 + ch];
      acc[0][c] = fmaf(v0.x, bw, acc[0][c]);
      acc[1][c] = fmaf(v0.y, bw, acc[1][c]);
      acc[2][c] = fmaf(v0.z, bw, acc[2][c]);
      acc[3][c] = fmaf(v0.w, bw, acc[3][c]);
      acc[4][c] = fmaf(v1.x, bw, acc[4][c]);
      acc[5][c] = fmaf(v1.y, bw, acc[5][c]);
      acc[6][c] = fmaf(v1.z, bw, acc[6][c]);
      acc[7][c] = fmaf(v1.w, bw, acc[7][c]);
    }
  }

  // apply depthwise weights (+ band bias) per element, accumulate per patch
  float dwt[8];
#pragma unroll
  for (int c = 0; c < 8; ++c) dwt[c] = 0.f;
#pragma unroll
  for (int e = 0; e < 8; ++e) {
    const int pp = p0 + ((e >> 2) << 3);
    const int qq = qb + (e & 3);
#pragma unroll
    for (int c = 0; c < 8; ++c)
      dwt[c] = fmaf(dw_w[c * 256 + pp * 16 + qq], acc[e][c] + band_b[c], dwt[c]);
  }
  // reduce over 4 lanes sharing a patch (lanes 4j..4j+3), then across 8 waves
#pragma unroll
  for (int c = 0; c < 8; ++c) {
    dwt[c] += __shfl_xor(dwt[c], 1, 64);
    dwt[c] += __shfl_xor(dwt[c], 2, 64);
  }
  __shared__ float part[8][16][8];
  if ((t & 3) == 0) {
#pragma unroll
    for (int c = 0; c < 8; ++c) part[t >> 6][j][c] = dwt[c];
  }
  __syncthreads();
  if (t < 128) {
    const int jj = t >> 3, c = t & 7;
    float s = 0.f;
#pragma unroll
    for (int w = 0; w < 8; ++w) s += part[w][jj][c];
    // layout: dw[b][i][j][c] (token-major, 8 contiguous per token)
    dw_out[(((size_t)b * 16 + ip) * 16 + jj) * 8 + c] = s;
  }
}

// ---------------------------------------------------------------------------
// K2: token pipeline: pw (8->192) + LN -> xb; router r1/r2 -> top2 x2 ->
// gated proto mix -> keys. 16 tokens per block, 256 threads, 512 blocks.
// ---------------------------------------------------------------------------
__global__ __launch_bounds__(256) void k2_token(
    const float* __restrict__ dw, const float* __restrict__ pw_w,
    const float* __restrict__ pe_ln_w, const float* __restrict__ pe_ln_b,
    const float* __restrict__ spec_proto, const float* __restrict__ spat_proto,
    const float* __restrict__ r1_w, const float* __restrict__ r1_b,
    const float* __restrict__ r2_w, const float* __restrict__ r2_b,
    const float* __restrict__ key_w, const float* __restrict__ pos_bias,
    float* __restrict__ xb_out, float* __restrict__ keys_out) {
  const int t = threadIdx.x;
  const int tx = t & 63, ty = t >> 6;
  const int tok0 = blockIdx.x * 16;

  __shared__ float dw8s[16][8];
  __shared__ float xnT[192][20];
  __shared__ float hT[128][20];
  __shared__ float rlS[16][48];
  __shared__ float topwS[16][4];
  __shared__ int   topiS[16][4];
  __shared__ float mixT[200][20];

  if (t < 128) {
    const int tt = t >> 3, c = t & 7;
    dw8s[tt][c] = dw[((size_t)tok0 + tt) * 8 + c];
  }
  __syncthreads();

  // ---- phase 1: pw + LN, write xb and xnT ----
  {
    const int tt = t >> 4, lg = t & 15;
    float pre[12];
    float sm = 0.f;
#pragma unroll
    for (int m = 0; m < 12; ++m) {
      const int d = lg + 16 * m;
      const float4 pa = *(const float4*)&pw_w[d * 8];
      const float4 pb = *(const float4*)&pw_w[d * 8 + 4];
      float p = pa.x * dw8s[tt][0] + pa.y * dw8s[tt][1] + pa.z * dw8s[tt][2] +
                pa.w * dw8s[tt][3] + pb.x * dw8s[tt][4] + pb.y * dw8s[tt][5] +
                pb.z * dw8s[tt][6] + pb.w * dw8s[tt][7];
      pre[m] = p;
      sm += p;
    }
    sm = sum16(sm);
    const float mean = sm * (1.f / 192.f);
    float vv = 0.f;
#pragma unroll
    for (int m = 0; m < 12; ++m) {
      const float d0 = pre[m] - mean;
      vv = fmaf(d0, d0, vv);
    }
    vv = sum16(vv);
    const float inv = rsqrtf(vv * (1.f / 192.f) + 1e-5f);
#pragma unroll
    for (int m = 0; m < 12; ++m) {
      const int d = lg + 16 * m;
      const float xv = (pre[m] - mean) * inv * pe_ln_w[d] + pe_ln_b[d];
      xnT[d][tt] = xv;
      xb_out[((size_t)tok0 + tt) * 192 + d] = xv;
    }
  }
  __syncthreads();

  // ---- phase 2: r1 GEMM (192->128) + gelu ----
  {
    float a1[4][2];
#pragma unroll
    for (int i = 0; i < 4; ++i) {
      a1[i][0] = r1_b[tx];
      a1[i][1] = r1_b[tx + 64];
    }
    for (int k = 0; k < 192; ++k) {
      const float4 a = *(const float4*)&xnT[k][ty << 2];
      const float av[4] = {a.x, a.y, a.z, a.w};
#pragma unroll
      for (int m = 0; m < 2; ++m) {
        const float w = r1_w[k * 128 + tx + 64 * m];
#pragma unroll
        for (int i = 0; i < 4; ++i) a1[i][m] = fmaf(av[i], w, a1[i][m]);
      }
    }
#pragma unroll
    for (int i = 0; i < 4; ++i) {
      hT[tx][(ty << 2) + i] = gelu_f(a1[i][0]);
      hT[tx + 64][(ty << 2) + i] = gelu_f(a1[i][1]);
    }
  }
  __syncthreads();

  // ---- phase 3: r2 GEMM (128->48) ----
  if (tx < 48) {
    float a2[4];
#pragma unroll
    for (int i = 0; i < 4; ++i) a2[i] = r2_b[tx];
    for (int k = 0; k < 128; ++k) {
      const float4 a = *(const float4*)&hT[k][ty << 2];
      const float av[4] = {a.x, a.y, a.z, a.w};
      const float w = r2_w[k * 48 + tx];
#pragma unroll
      for (int i = 0; i < 4; ++i) a2[i] = fmaf(av[i], w, a2[i]);
    }
#pragma unroll
    for (int i = 0; i < 4; ++i) rlS[(ty << 2) + i][tx] = a2[i];
  }
  __syncthreads();

  // ---- phase 4: top-2 + temperature softmax, per token x {spec,spat} ----
  if (t < 32) {
    const int tt = t >> 1, half = t & 1;
    const float* base = &rlS[tt][half * 24];
    float v0 = -1e30f, v1 = -1e30f;
    int i0 = 0, i1 = 0;
    for (int k = 0; k < 24; ++k) {
      const float vv = base[k];
      if (vv > v0) { v1 = v0; i1 = i0; v0 = vv; i0 = k; }
      else if (vv > v1) { v1 = vv; i1 = k; }
    }
    const float tau = (float)(0.07 + 1e-8);
    const float e1 = expf((v1 - v0) / tau);
    const float inv = 1.f / (1.f + e1);
    topwS[tt][half * 2] = inv;
    topwS[tt][half * 2 + 1] = e1 * inv;
    topiS[tt][half * 2] = i0;
    topiS[tt][half * 2 + 1] = i1;
  }
  __syncthreads();

  // ---- phase 5: build mixed prototype matrix mixT[200][16] ----
#pragma unroll
  for (int r = 0; r < 13; ++r) {
    const int f = t + 256 * r;
    if (f < 3200) {
      const int c = f >> 4, tt = f & 15;
      float val;
      if (c < 8) {
        val = topwS[tt][0] * spec_proto[topiS[tt][0] * 8 + c] +
              topwS[tt][1] * spec_proto[topiS[tt][1] * 8 + c];
      } else {
        const int cc = c - 8;
        val = topwS[tt][2] * spat_proto[topiS[tt][2] * 192 + cc] +
              topwS[tt][3] * spat_proto[topiS[tt][3] * 192 + cc];
      }
      mixT[c][tt] = val;
    }
  }
  __syncthreads();

  // ---- phase 6: keys GEMM (200->192) + pos_bias ----
  {
    float ak[4][3];
#pragma unroll
    for (int i = 0; i < 4; ++i)
#pragma unroll
      for (int m = 0; m < 3; ++m) ak[i][m] = pos_bias[tx + 64 * m];
    for (int k = 0; k < 200; ++k) {
      const float4 a = *(const float4*)&mixT[k][ty << 2];
      const float av[4] = {a.x, a.y, a.z, a.w};
#pragma unroll
      for (int m = 0; m < 3; ++m) {
        const float w = key_w[k * 192 + tx + 64 * m];
#pragma unroll
        for (int i = 0; i < 4; ++i) ak[i][m] = fmaf(av[i], w, ak[i][m]);
      }
    }
#pragma unroll
    for (int i = 0; i < 4; ++i) {
      const size_t row = ((size_t)tok0 + (ty << 2) + i) * 192;
#pragma unroll
      for (int m = 0; m < 3; ++m) keys_out[row + tx + 64 * m] = ak[i][m];
    }
  }
}

// ---------------------------------------------------------------------------
// K3a: xn = LN(xb); q = xn@qw -> softmax -> qs; v = xn@vw.
// 16 tokens / block, 512 blocks, 256 threads.
// ---------------------------------------------------------------------------
__global__ __launch_bounds__(256) void k3a_qv(
    const float* __restrict__ xb, const float* __restrict__ lnw,
    const float* __restrict__ lnb, const float* __restrict__ qw,
    const float* __restrict__ vw, float* __restrict__ qs_out,
    float* __restrict__ v_out, int depth) {
  const int t = threadIdx.x;
  const int tx = t & 63, ty = t >> 6;
  const int tok0 = blockIdx.x * 16;
  __shared__ float xnT[192][20];
  {
    const int tt = t >> 4, lg = t & 15;
    const float* xrow = xb + ((size_t)tok0 + tt) * 192;
    float vals[12];
    float sm = 0.f;
#pragma unroll
    for (int m = 0; m < 12; ++m) {
      vals[m] = xrow[lg + 16 * m];
      sm += vals[m];
    }
    sm = sum16(sm);
    const float mean = sm * (1.f / 192.f);
    float vv = 0.f;
#pragma unroll
    for (int m = 0; m < 12; ++m) {
      const float d0 = vals[m] - mean;
      vv = fmaf(d0, d0, vv);
    }
    vv = sum16(vv);
    const float inv = rsqrtf(vv * (1.f / 192.f) + 1e-5f);
    const float* lw = lnw + depth * 192;
    const float* lb = lnb + depth * 192;
#pragma unroll
    for (int m = 0; m < 12; ++m) {
      const int d = lg + 16 * m;
      xnT[d][tt] = (vals[m] - mean) * inv * lw[d] + lb[d];
    }
  }
  __syncthreads();

  float accq[4][3], accv[4][3];
#pragma unroll
  for (int i = 0; i < 4; ++i)
#pragma unroll
    for (int m = 0; m < 3; ++m) { accq[i][m] = 0.f; accv[i][m] = 0.f; }

  const float* qp = qw + (size_t)depth * 192 * 192;
  const float* vp = vw + (size_t)depth * 192 * 192;
  for (int k = 0; k < 192; ++k) {
    const float4 a = *(const float4*)&xnT[k][ty << 2];
    const float av[4] = {a.x, a.y, a.z, a.w};
#pragma unroll
    for (int m = 0; m < 3; ++m) {
      const float wq = qp[k * 192 + tx + 64 * m];
      const float wv = vp[k * 192 + tx + 64 * m];
#pragma unroll
      for (int i = 0; i < 4; ++i) {
        accq[i][m] = fmaf(av[i], wq, accq[i][m]);
        accv[i][m] = fmaf(av[i], wv, accv[i][m]);
      }
    }
  }
#pragma unroll
  for (int i = 0; i < 4; ++i) {
    const size_t row = ((size_t)tok0 + (ty << 2) + i) * 192;
#pragma unroll
    for (int m = 0; m < 3; ++m) v_out[row + tx + 64 * m] = accv[i][m];
    float mx = fmaxf(accq[i][0], fmaxf(accq[i][1], accq[i][2]));
    mx = wmax64(mx);
    const float e0 = expf(accq[i][0] - mx);
    const float e1 = expf(accq[i][1] - mx);
    const float e2 = expf(accq[i][2] - mx);
    const float ssum = wsum64(e0 + e1 + e2);
    const float inv = 1.f / ssum;
    qs_out[row + tx] = e0 * inv;
    qs_out[row + tx + 64] = e1 * inv;
    qs_out[row + tx + 128] = e2 * inv;
  }
}

// ---------------------------------------------------------------------------
// K3b: KV[b] = keys[b]^T @ v[b]  (192x192, K=256 tokens).
// Grid: 32 batches x 8 c-tiles (24 rows each) = 256 blocks. No partials.
// ---------------------------------------------------------------------------
__global__ __launch_bounds__(256) void k3b_kv(
    const float* __restrict__ keys, const float* __restrict__ v,
    float* __restrict__ kv) {
  const int b = blockIdx.x >> 3, ct = blockIdx.x & 7;
  const int c0 = ct * 24;
  const int t = threadIdx.x;
  const int ci = t >> 6;  // wave id: 6 c-rows each
  const int di = t & 63;
  __shared__ float ks[16][24];
  __shared__ float vs[16][192];
  float acc[6][3];
#pragma unroll
  for (int i = 0; i < 6; ++i)
#pragma unroll
    for (int u = 0; u < 3; ++u) acc[i][u] = 0.f;

  for (int s = 0; s < 16; ++s) {
    const size_t tokbase = (size_t)b * 256 + s * 16;
    if (t < 96) {
      const int nn = t / 6, u = t % 6;
      *(float4*)&ks[nn][u * 4] =
          *(const float4*)&keys[(tokbase + nn) * 192 + c0 + u * 4];
    }
    {
      const float4* vp = (const float4*)(v + tokbase * 192);
      float4* vsp = (float4*)vs;
#pragma unroll
      for (int r = 0; r < 3; ++r) vsp[t + 256 * r] = vp[t + 256 * r];
    }
    __syncthreads();
#pragma unroll 4
    for (int n = 0; n < 16; ++n) {
      float kc[6];
      *(float2*)&kc[0] = *(const float2*)&ks[n][ci * 6];
      *(float2*)&kc[2] = *(const float2*)&ks[n][ci * 6 + 2];
      *(float2*)&kc[4] = *(const float2*)&ks[n][ci * 6 + 4];
      const float vd0 = vs[n][di];
      const float vd1 = vs[n][di + 64];
      const float vd2 = vs[n][di + 128];
#pragma unroll
      for (int i = 0; i < 6; ++i) {
        acc[i][0] = fmaf(kc[i], vd0, acc[i][0]);
        acc[i][1] = fmaf(kc[i], vd1, acc[i][1]);
        acc[i][2] = fmaf(kc[i], vd2, acc[i][2]);
      }
    }
    __syncthreads();
  }
  float* outp = kv + (size_t)b * 36864;
#pragma unroll
  for (int i = 0; i < 6; ++i)
#pragma unroll
    for (int u = 0; u < 3; ++u)
      outp[(c0 + ci * 6 + i) * 192 + di + 64 * u] = acc[i][u];
}

// ---------------------------------------------------------------------------
// K3c: out = qs@KV; xb += out*g1; xn2 = LN(xb); ff = gelu(xn2@f1+b1)@f2+b2;
// xb += ff*g2.  16 tokens / block, 512 blocks, 256 threads.
// ---------------------------------------------------------------------------
__global__ __launch_bounds__(256) void k3c_ff(
    float* __restrict__ xb, const float* __restrict__ qs,
    const float* __restrict__ kv, const float* __restrict__ lnw,
    const float* __restrict__ lnb, const float* __restrict__ f1w,
    const float* __restrict__ f1b, const float* __restrict__ f2w,
    const float* __restrict__ f2b, const float* __restrict__ g1,
    const float* __restrict__ g2, int depth) {
  const int t = threadIdx.x;
  const int tx = t & 63, ty = t >> 6;
  const int tok0 = blockIdx.x * 16;
  const int b = blockIdx.x >> 4;
  __shared__ float aT[192][20];   // qsT, then xn2T
  __shared__ float fT[384][20];   // ff1T

  // stage qs^T
#pragma unroll
  for (int r = 0; r < 12; ++r) {
    const int f = t + 256 * r;
    const int d = f % 192, tt = f / 192;
    aT[d][tt] = qs[((size_t)tok0 + tt) * 192 + d];
  }
  __syncthreads();

  // out = qs @ KV
  float o1[4][3];
#pragma unroll
  for (int i = 0; i < 4; ++i)
#pragma unroll
    for (int m = 0; m < 3; ++m) o1[i][m] = 0.f;
  const float* kvb = kv + (size_t)b * 36864;
  for (int k = 0; k < 192; ++k) {
    const float4 a = *(const float4*)&aT[k][ty << 2];
    const float av[4] = {a.x, a.y, a.z, a.w};
#pragma unroll
    for (int m = 0; m < 3; ++m) {
      const float w = kvb[k * 192 + tx + 64 * m];
#pragma unroll
      for (int i = 0; i < 4; ++i) o1[i][m] = fmaf(av[i], w, o1[i][m]);
    }
  }

  // residual 1
  float xbn[4][3];
  const float* g1p = g1 + depth * 192;
#pragma unroll
  for (int i = 0; i < 4; ++i) {
    const size_t row = ((size_t)tok0 + (ty << 2) + i) * 192;
#pragma unroll
    for (int m = 0; m < 3; ++m)
      xbn[i][m] = xb[row + tx + 64 * m] + o1[i][m] * g1p[tx + 64 * m];
  }
  __syncthreads();  // aT free

  // LN per token (wave owns 4 tokens; row spread over 64 lanes x 3 cols)
  const float* lw = lnw + depth * 192;
  const float* lb = lnb + depth * 192;
#pragma unroll
  for (int i = 0; i < 4; ++i) {
    float sm = xbn[i][0] + xbn[i][1] + xbn[i][2];
    sm = wsum64(sm);
    const float mean = sm * (1.f / 192.f);
    float vv = 0.f;
#pragma unroll
    for (int m = 0; m < 3; ++m) {
      const float d0 = xbn[i][m] - mean;
      vv = fmaf(d0, d0, vv);
    }
    vv = wsum64(vv);
    const float inv = rsqrtf(vv * (1.f / 192.f) + 1e-5f);
#pragma unroll
    for (int m = 0; m < 3; ++m) {
      const int col = tx + 64 * m;
      aT[col][(ty << 2) + i] = (xbn[i][m] - mean) * inv * lw[col] + lb[col];
    }
  }
  __syncthreads();

  // ff1 = gelu(xn2 @ f1 + b1)
  float h[4][6];
#pragma unroll
  for (int i = 0; i < 4; ++i)
#pragma unroll
    for (int m = 0; m < 6; ++m) h[i][m] = 0.f;
  const float* f1p = f1w + (size_t)depth * 192 * 384;
  for (int k = 0; k < 192; ++k) {
    const float4 a = *(const float4*)&aT[k][ty << 2];
    const float av[4] = {a.x, a.y, a.z, a.w};
#pragma unroll
    for (int m = 0; m < 6; ++m) {
      const float w = f1p[k * 384 + tx + 64 * m];
#pragma unroll
      for (int i = 0; i < 4; ++i) h[i][m] = fmaf(av[i], w, h[i][m]);
    }
  }
  const float* b1p = f1b + depth * 384;
#pragma unroll
  for (int i = 0; i < 4; ++i)
#pragma unroll
    for (int m = 0; m < 6; ++m) {
      const int col = tx + 64 * m;
      fT[col][(ty << 2) + i] = gelu_f(h[i][m] + b1p[col]);
    }
  __syncthreads();

  // ff2 + residual 2
  float o2[4][3];
#pragma unroll
  for (int i = 0; i < 4; ++i)
#pragma unroll
    for (int m = 0; m < 3; ++m) o2[i][m] = 0.f;
  const float* f2p = f2w + (size_t)depth * 384 * 192;
  for (int k = 0; k < 384; ++k) {
    const float4 a = *(const float4*)&fT[k][ty << 2];
    const float av[4] = {a.x, a.y, a.z, a.w};
#pragma unroll
    for (int m = 0; m < 3; ++m) {
      const float w = f2p[k * 192 + tx + 64 * m];
#pragma unroll
      for (int i = 0; i < 4; ++i) o2[i][m] = fmaf(av[i], w, o2[i][m]);
    }
  }
  const float* b2p = f2b + depth * 192;
  const float* g2p = g2 + depth * 192;
#pragma unroll
  for (int i = 0; i < 4; ++i) {
    const size_t row = ((size_t)tok0 + (ty << 2) + i) * 192;
#pragma unroll
    for (int m = 0; m < 3; ++m) {
      const int col = tx + 64 * m;
      xb[row + col] = xbn[i][m] + (o2[i][m] + b2p[col]) * g2p[col];
    }
  }
}

// ---------------------------------------------------------------------------
// K4: feat = LN(mean_n xb); out = feat @ head_w + head_b. 32 blocks x 192.
// ---------------------------------------------------------------------------
__global__ __launch_bounds__(192) void k4_head(
    const float* __restrict__ xb, const float* __restrict__ flnw,
    const float* __restrict__ flnb, const float* __restrict__ hw,
    const float* __restrict__ hb, float* __restrict__ out) {
  const int b = blockIdx.x, t = threadIdx.x;
  const int w = t >> 6, lane = t & 63;
  float s = 0.f;
  const float* base = xb + (size_t)b * 256 * 192 + t;
  for (int n = 0; n < 256; ++n) s += base[n * 192];
  const float feat_pre = s * (1.f / 256.f);
  __shared__ float red[3];
  __shared__ float feat[192];
  float sm = wsum64(feat_pre);
  if (lane == 0) red[w] = sm;
  __syncthreads();
  const float mean = (red[0] + red[1] + red[2]) * (1.f / 192.f);
  __syncthreads();
  const float dd = feat_pre - mean;
  sm = wsum64(dd * dd);
  if (lane == 0) red[w] = sm;
  __syncthreads();
  const float var = (red[0] + red[1] + red[2]) * (1.f / 192.f);
  feat[t] = dd * rsqrtf(var + 1e-5f) * flnw[t] + flnb[t];
  __syncthreads();
  if (t < 9) {
    float a = hb[t];
    for (int d = 0; d < 192; ++d) a = fmaf(feat[d], hw[d * 9 + t], a);
    out[b * 9 + t] = a;
  }
}

// ---------------------------------------------------------------------------
extern "C" void kernel_launch(void* const* d_in, const int* in_sizes, int n_in,
                              void* d_out, int out_size, void* d_ws, size_t ws_size,
                              hipStream_t stream) {
  (void)in_sizes; (void)n_in; (void)out_size; (void)ws_size;
  const float* x          = (const float*)d_in[0];
  const float* band_w     = (const float*)d_in[1];
  const float* band_b     = (const float*)d_in[2];
  const float* dw_w       = (const float*)d_in[3];
  const float* pw_w       = (const float*)d_in[4];
  const float* pe_ln_w    = (const float*)d_in[5];
  const float* pe_ln_b    = (const float*)d_in[6];
  const float* spec_proto = (const float*)d_in[7];
  const float* spat_proto = (const float*)d_in[8];
  const float* r1_w       = (const float*)d_in[9];
  const float* r1_b       = (const float*)d_in[10];
  const float* r2_w       = (const float*)d_in[11];
  const float* r2_b       = (const float*)d_in[12];
  const float* key_w      = (const float*)d_in[13];
  const float* pos_bias   = (const float*)d_in[14];
  const float* blk_ln_w   = (const float*)d_in[15];
  const float* blk_ln_b   = (const float*)d_in[16];
  const float* blk_q_w    = (const float*)d_in[17];
  const float* blk_v_w    = (const float*)d_in[18];
  const float* blk_f1_w   = (const float*)d_in[19];
  const float* blk_f1_b   = (const float*)d_in[20];
  const float* blk_f2_w   = (const float*)d_in[21];
  const float* blk_f2_b   = (const float*)d_in[22];
  const float* blk_g1     = (const float*)d_in[23];
  const float* blk_g2     = (const float*)d_in[24];
  const float* fin_ln_w   = (const float*)d_in[25];
  const float* fin_ln_b   = (const float*)d_in[26];
  const float* head_w     = (const float*)d_in[27];
  const float* head_b     = (const float*)d_in[28];

  float* ws   = (float*)d_ws;
  float* dw   = ws;                    // 65,536
  float* xbuf = dw + 65536;            // 1,572,864
  float* keys = xbuf + 1572864;        // 1,572,864
  float* qs   = keys + 1572864;        // 1,572,864
  float* vbuf = qs + 1572864;          // 1,572,864
  float* kv   = vbuf + 1572864;        // 1,179,648   (total ~30.1 MB)

  k1_band_dw<<<512, 512, 0, stream>>>(x, band_w, band_b, dw_w, dw);
  k2_token<<<512, 256, 0, stream>>>(dw, pw_w, pe_ln_w, pe_ln_b, spec_proto,
                                    spat_proto, r1_w, r1_b, r2_w, r2_b, key_w,
                                    pos_bias, xbuf, keys);
  for (int d = 0; d < 3; ++d) {
    k3a_qv<<<512, 256, 0, stream>>>(xbuf, blk_ln_w, blk_ln_b, blk_q_w, blk_v_w,
                                    qs, vbuf, d);
    k3b_kv<<<256, 256, 0, stream>>>(keys, vbuf, kv);
    k3c_ff<<<512, 256, 0, stream>>>(xbuf, qs, kv, blk_ln_w, blk_ln_b, blk_f1_w,
                                    blk_f1_b, blk_f2_w, blk_f2_b, blk_g1,
                                    blk_g2, d);
  }
  k4_head<<<32, 192, 0, stream>>>(xbuf, fin_ln_w, fin_ln_b, head_w, head_b,
                                  (float*)d_out);
}